// Round 6
// baseline (189.034 us; speedup 1.0000x reference)
//
#include <hip/hip_runtime.h>
#include <hip/hip_bf16.h>

typedef short short8 __attribute__((ext_vector_type(8)));
typedef float f32x4  __attribute__((ext_vector_type(4)));

static constexpr int   NPB  = 16384;
static constexpr int   NR   = 4 * NPB;       // 65536 rays
static constexpr int   NS   = 16;
static constexpr int   H    = 128;
static constexpr int   NPTS = NR * NS;       // 1,048,576 march points
static constexpr int   NCHUNK2 = NR / 8;     // 8192 chunks of 8 rays x 16 steps
static constexpr int   FIXCAP = 131072;
static constexpr float FARV = 2.4f;
static constexpr float EPSF = 1.1920928955078125e-07f;
// march f error with A=bf16-RNE only (W2 hi+lo): RMS ~1e-3, worst ~0.03.
// R9/R13 proved this config correctness-safe at FTHRESH=0.03.
static constexpr float FTHRESH = 0.03f;

// NOTE (R12): never declare __launch_bounds__ > 2 waves/EU on MFMA kernels.
// NOTE (R15): do NOT interleave stage1(c+1) VALU with stage2(c) MFMA.
// NOTE (R17/R18): extra barrier removal, mt-unroll, accumulator-split all
// neutral — compiler schedule already optimal; residual idle is barrier-drain.
// NOTE (R21/R21b): affine stage-1; arch-VGPR drop raised occupancy 19->33%.
// NOTE (R22): k_fix wave-per-point. R24 4-pt batching: k_fix was already
// small post-R22 — the R24 gain (-12us) was refine grid 1280->4096.
// NOTE (R23): swapped MFMA (C[n][point]); march now structure-bound
// (MFMA 33% + VALU 41% + ~25% barrier-drain idle).
// NOTE (R25): refine seeds flo/fhi from f_all via state.y/.w (reference
// semantics; post-fix values are sign-exact) -> 10 eval rounds -> 8.
// Idle refine blocks early-return BEFORE fragment prologue. s_setprio(1)
// around MFMA clusters (independent-block regime, T5).

// ---------------- bf16 helpers ---------------------------------------------
__device__ __forceinline__ unsigned bf16hi(float x) {
    unsigned u = __float_as_uint(x);
    return (u + 0x7FFFu + ((u >> 16) & 1u)) >> 16;
}
__device__ __forceinline__ void split_bf16(float x, short& hi, short& lo) {
    unsigned h = bf16hi(x);
    float hf = __uint_as_float(h << 16);
    unsigned l = __float_as_uint(x - hf) >> 16;
    hi = (short)h; lo = (short)l;
}
// packed RNE f32x2 -> bf16x2 (v_cvt_pk_bf16_f32 on gfx950)
__device__ __forceinline__ unsigned pk_bf16(float a, float b) {
    __hip_bfloat162 p = __float22bfloat162_rn(make_float2(a, b));
    unsigned u;
    __builtin_memcpy(&u, &p, sizeof(u));
    return u;
}

// ---------------- setup: cv vectors + W2 MFMA packing + counters -----------
__global__ void k_setup(const float* __restrict__ W1, const float* __restrict__ b1,
                        const float* __restrict__ W2, const float* __restrict__ feat,
                        float* __restrict__ cva, short* __restrict__ w2f,
                        int* __restrict__ count, int* __restrict__ fixcnt)
{
    int t = blockIdx.x * blockDim.x + threadIdx.x;   // 4096 threads
    if (t == 0) { *count = 0; *fixcnt = 0; }
    if (t < 4 * H) {                                 // cv = b1 + feat @ W1[3:35]
        int b = t >> 7, kk = t & (H - 1);
        float acc = b1[kk];
#pragma unroll
        for (int i = 0; i < 32; ++i)
            acc = fmaf(feat[b * 32 + i], W1[(3 + i) * H + kk], acc);
        cva[b * H + kk] = acc;
    }
    {                                                // MFMA W2-fragments (hi/lo)
        int lane = t & 63, ks = (t >> 6) & 3, part = (t >> 8) & 1;
        int nt = (t >> 9) & 1, w = (t >> 10) & 3;
        int n = w * 32 + nt * 16 + (lane & 15);
        int kb = ks * 32 + (lane >> 4) * 8;
        short8 v;
#pragma unroll
        for (int j = 0; j < 8; ++j) {
            short hi, lo;
            split_bf16(W2[(kb + j) * H + n], hi, lo);
            v[j] = part ? lo : hi;
        }
        ((short8*)w2f)[((w * 4 + nt * 2 + part) * 4 + ks) * 64 + lane] = v;
    }
}

// ---------------- Phase A: MFMA march (8 rays x 16 steps per chunk) --------
// R13 numerics; R21b affine stage 1; R23 swapped-operand stage 2.
// Point order in chunk: m = s*8 + rr; tile mt = s>>1, B-col = (s&1)*8+rr.
__global__ __launch_bounds__(256, 2) void k_marchx(
    const float* __restrict__ ray0, const float* __restrict__ dirs,
    const float* __restrict__ W1,   const float* __restrict__ cva,
    const float* __restrict__ b2,   const float* __restrict__ W3,
    const float* __restrict__ b3p,  const short* __restrict__ w2f,
    float* __restrict__ f_all, int* __restrict__ fixlist, int* __restrict__ fixcnt)
{
    __shared__ __align__(16) short hAhi[16384];      // 128 pts x 128 k (32 KB)
    __shared__ float fpart[2][4][128];               // ping-pong
    const int tid = threadIdx.x;
    const int w = tid >> 6, lane = tid & 63;
    const int q = lane >> 4, ln15 = lane & 15;

    const short8* wf8 = (const short8*)w2f;
    short8 Bh0[4], Bl0[4], Bh1[4], Bl1[4];
#pragma unroll
    for (int ks = 0; ks < 4; ++ks) {
        Bh0[ks] = wf8[((w * 4 + 0) * 4 + ks) * 64 + lane];
        Bl0[ks] = wf8[((w * 4 + 1) * 4 + ks) * 64 + lane];
        Bh1[ks] = wf8[((w * 4 + 2) * 4 + ks) * 64 + lane];
        Bl1[ks] = wf8[((w * 4 + 3) * 4 + ks) * 64 + lane];
    }
    // R23: per-lane n-axis constants (n = w*32 + [0,16) + q*4 + reg)
    const int nb0 = w * 32 + q * 4;
    float b2a[4], b2b[4], w3a[4], w3b[4];
#pragma unroll
    for (int reg = 0; reg < 4; ++reg) {
        b2a[reg] = b2[nb0 + reg];       b2b[reg] = b2[nb0 + 16 + reg];
        w3a[reg] = W3[nb0 + reg];       w3b[reg] = W3[nb0 + 16 + reg];
    }
    const float b3v  = *b3p;

    // ---- stage-1 thread-constant setup (affine stage 1) ----
    const int rr = tid & 7;                 // ray within chunk
    const int kt = tid >> 3;                // k-quad index, k = 4*kt..4*kt+3
    const int qp = (tid >> 4) & 3;
    const int j0 = ((tid >> 3) & 1) * 4;
    short* hwp = hAhi + ((w * 64 + rr + 16 * qp) * 8 + j0);
    const float4 wxv = ((const float4*)W1)[kt];
    const float4 wyv = ((const float4*)(W1 + H))[kt];
    const float4 wzv = ((const float4*)(W1 + 2 * H))[kt];

    int pp = 0;
    for (int c = blockIdx.x; c < NCHUNK2; c += gridDim.x) {
        // ---- stage 1: base/slope per (ray, 4k), then 16 steps x 1 fma/k
        {
            int r = c * 8 + rr;
            float ox = ray0[3 * r], oy = ray0[3 * r + 1], oz = ray0[3 * r + 2];
            float dx = dirs[3 * r], dy = dirs[3 * r + 1], dz = dirs[3 * r + 2];
            const float4 cvv = ((const float4*)(cva + (r >> 14) * H))[kt];
            float bb0 = fmaf(ox, wxv.x, fmaf(oy, wyv.x, fmaf(oz, wzv.x, cvv.x)));
            float bb1 = fmaf(ox, wxv.y, fmaf(oy, wyv.y, fmaf(oz, wzv.y, cvv.y)));
            float bb2 = fmaf(ox, wxv.z, fmaf(oy, wyv.z, fmaf(oz, wzv.z, cvv.z)));
            float bb3 = fmaf(ox, wxv.w, fmaf(oy, wyv.w, fmaf(oz, wzv.w, cvv.w)));
            float sl0 = fmaf(dx, wxv.x, fmaf(dy, wyv.x, dz * wzv.x));
            float sl1 = fmaf(dx, wxv.y, fmaf(dy, wyv.y, dz * wzv.y));
            float sl2 = fmaf(dx, wxv.z, fmaf(dy, wyv.z, dz * wzv.z));
            float sl3 = fmaf(dx, wxv.w, fmaf(dy, wyv.w, dz * wzv.w));
#pragma unroll
            for (int s = 0; s < NS; ++s) {
                const float d = ((float)s * (1.0f / 15.0f)) * FARV;
                float h0 = fmaxf(fmaf(d, sl0, bb0), 0.0f);
                float h1 = fmaxf(fmaf(d, sl1, bb1), 0.0f);
                float h2 = fmaxf(fmaf(d, sl2, bb2), 0.0f);
                float h3 = fmaxf(fmaf(d, sl3, bb3), 0.0f);
                uint2 u;
                u.x = pk_bf16(h0, h1);
                u.y = pk_bf16(h2, h3);
                // per-s offset (shorts): (s>>1)*2048 + (s&1)*64  (compile-time)
                *(uint2*)(hwp + ((s >> 1) * 2048 + (s & 1) * 64)) = u;
            }
        }
        __syncthreads();
        // ---- stage 2: swapped MFMA per 16-point M-tile: C[n][point]
        const short8* hi8 = (const short8*)hAhi;
#pragma unroll 2
        for (int mt = 0; mt < 8; ++mt) {
            short8 Hh[4];
#pragma unroll
            for (int ks = 0; ks < 4; ++ks)
                Hh[ks] = hi8[(mt * 4 + ks) * 64 + lane];
            f32x4 a0 = {b2a[0], b2a[1], b2a[2], b2a[3]};  // b2 in acc init
            f32x4 a1 = {b2b[0], b2b[1], b2b[2], b2b[3]};
            __builtin_amdgcn_s_setprio(1);               // R25: T5
#pragma unroll
            for (int ks = 0; ks < 4; ++ks) {
                a0 = __builtin_amdgcn_mfma_f32_16x16x32_bf16(Bh0[ks], Hh[ks], a0, 0, 0, 0);
                a1 = __builtin_amdgcn_mfma_f32_16x16x32_bf16(Bh1[ks], Hh[ks], a1, 0, 0, 0);
                a0 = __builtin_amdgcn_mfma_f32_16x16x32_bf16(Bl0[ks], Hh[ks], a0, 0, 0, 0);
                a1 = __builtin_amdgcn_mfma_f32_16x16x32_bf16(Bl1[ks], Hh[ks], a1, 0, 0, 0);
            }
            __builtin_amdgcn_s_setprio(0);
            float fp0 = 0.0f, fp1 = 0.0f;
#pragma unroll
            for (int reg = 0; reg < 4; ++reg) {
                fp0 = fmaf(fmaxf(a0[reg], 0.f), w3a[reg], fp0);
                fp1 = fmaf(fmaxf(a1[reg], 0.f), w3b[reg], fp1);
            }
            float fp = fp0 + fp1;
            fp += __shfl_xor(fp, 16, 64);   // reduce over q (n-groups)
            fp += __shfl_xor(fp, 32, 64);
            if (lane < 16) fpart[pp][w][mt * 16 + lane] = fp;
        }
        __syncthreads();
        // ---- stage 3: finalize 128 points (fpart ping-pong: no 3rd barrier)
        if (tid < 128) {
            float f = fpart[pp][0][tid] + fpart[pp][1][tid] + fpart[pp][2][tid]
                    + fpart[pp][3][tid] + b3v;
            int s = tid >> 3, rb = tid & 7;
            int P = s * NR + c * 8 + rb;             // same s*NR+r encoding
            f_all[P] = f;
            if (fabsf(f) < FTHRESH) {
                int sl = atomicAdd(fixcnt, 1);
                if (sl < FIXCAP) fixlist[sl] = P;
            }
        }
        pp ^= 1;
    }
}

// ---------------- fp32 re-eval of near-zero points (4 pts/wave, R24) -------
__global__ __launch_bounds__(256) void k_fix(
    const float* __restrict__ ray0, const float* __restrict__ dirs,
    const float* __restrict__ W1,   const float* __restrict__ cva,
    const float* __restrict__ W2,   const float* __restrict__ b2,
    const float* __restrict__ W3,   const float* __restrict__ b3p,
    const int* __restrict__ fixcnt, const int* __restrict__ fixlist,
    float* __restrict__ f_all)
{
    __shared__ __align__(16) float hsh[4][128][4];   // [wave][k][point], 8 KB
    const int wv = threadIdx.x >> 6, lane = threadIdx.x & 63;
    unsigned fc = (unsigned)*fixcnt;
    if (fc > (unsigned)FIXCAP) fc = FIXCAP;

    const float w1x0 = W1[lane],           w1x1 = W1[64 + lane];
    const float w1y0 = W1[H + lane],       w1y1 = W1[H + 64 + lane];
    const float w1z0 = W1[2 * H + lane],   w1z1 = W1[2 * H + 64 + lane];
    const float w30  = W3[lane],           w31  = W3[64 + lane];
    const float b20  = b2[lane],           b21  = b2[64 + lane];
    const float b3v  = *b3p;

    for (unsigned i0 = (blockIdx.x * 4u + (unsigned)wv) * 4u; i0 < fc;
         i0 += gridDim.x * 16u) {
        int Pj[4];
#pragma unroll
        for (int j = 0; j < 4; ++j) {
            unsigned i = i0 + (unsigned)j;
            bool vld = (i < fc);
            int P = fixlist[vld ? i : i0] & (NPTS - 1);
            Pj[j] = vld ? P : -1;
            int r = P & (NR - 1), s = P >> 16;
            float d = ((float)s * (1.0f / 15.0f)) * FARV;
            float ox = ray0[3 * r], oy = ray0[3 * r + 1], oz = ray0[3 * r + 2];
            float dx = dirs[3 * r], dy = dirs[3 * r + 1], dz = dirs[3 * r + 2];
            float px = fmaf(d, dx, ox), py = fmaf(d, dy, oy), pz = fmaf(d, dz, oz);
            const float* __restrict__ cv = cva + (r >> 14) * H;
            float h0 = fmaf(px, w1x0, fmaf(py, w1y0, fmaf(pz, w1z0, cv[lane])));
            float h1 = fmaf(px, w1x1, fmaf(py, w1y1, fmaf(pz, w1z1, cv[64 + lane])));
            hsh[wv][lane][j]      = fmaxf(h0, 0.0f);
            hsh[wv][lane + 64][j] = fmaxf(h1, 0.0f);
        }
        // same-wave LDS write->read; compiler inserts the lgkmcnt wait.
        float a0[4] = {b20, b20, b20, b20};
        float a1[4] = {b21, b21, b21, b21};
#pragma unroll 4
        for (int k = 0; k < H; ++k) {
            float4 hk = *(const float4*)&hsh[wv][k][0];  // broadcast b128
            float w2l = W2[k * H + lane];
            float w2h = W2[k * H + 64 + lane];
            a0[0] = fmaf(hk.x, w2l, a0[0]);  a1[0] = fmaf(hk.x, w2h, a1[0]);
            a0[1] = fmaf(hk.y, w2l, a0[1]);  a1[1] = fmaf(hk.y, w2h, a1[1]);
            a0[2] = fmaf(hk.z, w2l, a0[2]);  a1[2] = fmaf(hk.z, w2h, a1[2]);
            a0[3] = fmaf(hk.w, w2l, a0[3]);  a1[3] = fmaf(hk.w, w2h, a1[3]);
        }
#pragma unroll
        for (int j = 0; j < 4; ++j) {
            float f = fmaf(fmaxf(a0[j], 0.f), w30, fmaxf(a1[j], 0.f) * w31);
#pragma unroll
            for (int off = 32; off; off >>= 1)
                f += __shfl_xor(f, off, 64);
            if (lane == 0 && Pj[j] >= 0) f_all[Pj[j]] = f + b3v;
        }
    }
}

// ---------------- crossing scan --------------------------------------------
// R25: state carries (dlo, f_low, dhi, f_high) — refine seeds from these.
__global__ void k_cross(
    const float* __restrict__ ray0, const float* __restrict__ dirs,
    const float* __restrict__ f_all,
    int* __restrict__ count, int* __restrict__ ids,
    float4* __restrict__ state, float* __restrict__ out)
{
    int r = blockIdx.x * blockDim.x + threadIdx.x;   // 65536 threads
    float fv[NS];
#pragma unroll
    for (int s = 0; s < NS; ++s) fv[s] = f_all[s * NR + r];
    int idx = -1;
#pragma unroll
    for (int s = NS - 2; s >= 0; --s) {
        if (fv[s] < 0.0f && fv[s + 1] >= 0.0f) idx = s;
    }
    if (idx < 0) {
        float ox = ray0[3 * r], oy = ray0[3 * r + 1], oz = ray0[3 * r + 2];
        float dx = dirs[3 * r], dy = dirs[3 * r + 1], dz = dirs[3 * r + 2];
        out[r] = FARV;
        out[NR + 3 * r + 0] = fmaf(FARV, dx, ox);
        out[NR + 3 * r + 1] = fmaf(FARV, dy, oy);
        out[NR + 3 * r + 2] = fmaf(FARV, dz, oz);
        out[4 * NR + r] = 0.0f;
    } else {
        int slot = atomicAdd(count, 1);
        ids[slot] = r;
        float flo = fv[idx], fhi = fv[idx + 1];
        float dlo = ((float)idx * (1.0f / 15.0f)) * FARV;
        float dhi = ((float)(idx + 1) * (1.0f / 15.0f)) * FARV;
        state[slot] = make_float4(dlo, flo, dhi, fhi);
    }
}

// ---------------- Phase B: MFMA secant refine (16 rays per block) ----------
// R13 structure; R23 swapped operands. R25: brackets seeded from state
// (reference semantics — no it0/1 re-eval): 8 secant rounds + final formula.
// Grid 4096 >= max groups: exactly 1 group per block; idle blocks return
// before the fragment prologue.
__global__ __launch_bounds__(256, 2) void k_refine(
    const float* __restrict__ ray0, const float* __restrict__ dirs,
    const float* __restrict__ W1,   const float* __restrict__ cva,
    const float* __restrict__ b2,   const float* __restrict__ W3,
    const float* __restrict__ b3p,  const short* __restrict__ w2f,
    const int* __restrict__ count,  const int* __restrict__ ids,
    const float4* __restrict__ state, float* __restrict__ out)
{
    __shared__ __align__(16) short hAhi[2048];       // 4 ks x 64 lanes x short8
    __shared__ __align__(16) short hAlo[2048];
    __shared__ float fpart[4][16];
    const int tid = threadIdx.x;
    const int w = tid >> 6, lane = tid & 63;
    const int q = lane >> 4, ln15 = lane & 15;

    unsigned cnt = (unsigned)*count;
    if (cnt > (unsigned)NR) cnt = (unsigned)NR;      // poison guard
    const unsigned g = blockIdx.x;                   // 1 group per block
    if (g * 16u >= cnt) return;                      // R25: pre-prologue exit

    const short8* wf8 = (const short8*)w2f;
    short8 Bh0[4], Bl0[4], Bh1[4], Bl1[4];
#pragma unroll
    for (int ks = 0; ks < 4; ++ks) {
        Bh0[ks] = wf8[((w * 4 + 0) * 4 + ks) * 64 + lane];
        Bl0[ks] = wf8[((w * 4 + 1) * 4 + ks) * 64 + lane];
        Bh1[ks] = wf8[((w * 4 + 2) * 4 + ks) * 64 + lane];
        Bl1[ks] = wf8[((w * 4 + 3) * 4 + ks) * 64 + lane];
    }
    // R23 per-lane n-axis constants
    const int nb0 = w * 32 + q * 4;
    float b2a[4], b2b[4], w3a[4], w3b[4];
#pragma unroll
    for (int reg = 0; reg < 4; ++reg) {
        b2a[reg] = b2[nb0 + reg];       b2b[reg] = b2[nb0 + 16 + reg];
        w3a[reg] = W3[nb0 + reg];       w3b[reg] = W3[nb0 + 16 + reg];
    }
    const float b3v  = *b3p;

    const int i4 = (w * 32 + q * 8) >> 2;
    const float4* W1x4 = (const float4*)(W1);
    const float4* W1y4 = (const float4*)(W1 + H);
    const float4* W1z4 = (const float4*)(W1 + 2 * H);
    const float4 x0 = W1x4[i4], x1 = W1x4[i4 + 1];
    const float4 y0 = W1y4[i4], y1 = W1y4[i4 + 1];
    const float4 z0 = W1z4[i4], z1 = W1z4[i4 + 1];

    uint4* hi4 = (uint4*)hAhi;
    uint4* lo4 = (uint4*)hAlo;
    const short8* hi8 = (const short8*)hAhi;
    const short8* lo8 = (const short8*)hAlo;

    {
        unsigned t = g * 16u + (unsigned)ln15;
        bool valid = (t < cnt);
        unsigned tc = valid ? t : (cnt - 1);
        int r = ids[tc] & (NR - 1);                  // poison guard
        float4 st = state[tc];
        float dlo = st.x, dhi = st.z;
        float flo = st.y, fhi = st.w;                // R25: seeded brackets
        float ox = ray0[3 * r], oy = ray0[3 * r + 1], oz = ray0[3 * r + 2];
        float dx = dirs[3 * r], dy = dirs[3 * r + 1], dz = dirs[3 * r + 2];
        const float4* cv4 = (const float4*)(cva + (r >> 14) * H);
        float4 c0 = cv4[i4], c1 = cv4[i4 + 1];
        float dp = 0.0f;

#pragma unroll 1
        for (int it = 0; it < 9; ++it) {
            // it 0..7: secant eval rounds; it 8: final formula only
            float dc  = fhi - flo;
            float den = copysignf(fmaxf(fabsf(dc), EPSF), dc);
            float dn  = dlo - (flo * (dhi - dlo)) / den;
            if (it == 8) { dp = dn; break; }
            // stage 1: h for ray ln15, 8 k values -> hi/lo bf16 -> LDS
            float px = fmaf(dn, dx, ox), py = fmaf(dn, dy, oy), pz = fmaf(dn, dz, oz);
            float hv[8];
            hv[0] = fmaf(px, x0.x, fmaf(py, y0.x, fmaf(pz, z0.x, c0.x)));
            hv[1] = fmaf(px, x0.y, fmaf(py, y0.y, fmaf(pz, z0.y, c0.y)));
            hv[2] = fmaf(px, x0.z, fmaf(py, y0.z, fmaf(pz, z0.z, c0.z)));
            hv[3] = fmaf(px, x0.w, fmaf(py, y0.w, fmaf(pz, z0.w, c0.w)));
            hv[4] = fmaf(px, x1.x, fmaf(py, y1.x, fmaf(pz, z1.x, c1.x)));
            hv[5] = fmaf(px, x1.y, fmaf(py, y1.y, fmaf(pz, z1.y, c1.y)));
            hv[6] = fmaf(px, x1.z, fmaf(py, y1.z, fmaf(pz, z1.z, c1.z)));
            hv[7] = fmaf(px, x1.w, fmaf(py, y1.w, fmaf(pz, z1.w, c1.w)));
            unsigned uh[4], ul[4];
#pragma unroll
            for (int jp = 0; jp < 4; ++jp) {
                float h0 = fmaxf(hv[2 * jp],     0.0f);
                float h1 = fmaxf(hv[2 * jp + 1], 0.0f);
                unsigned u = pk_bf16(h0, h1);
                float hf0 = __uint_as_float(u << 16);
                float hf1 = __uint_as_float(u & 0xFFFF0000u);
                ul[jp] = pk_bf16(h0 - hf0, h1 - hf1);
                uh[jp] = u;
            }
            hi4[w * 64 + lane] = make_uint4(uh[0], uh[1], uh[2], uh[3]);
            lo4[w * 64 + lane] = make_uint4(ul[0], ul[1], ul[2], ul[3]);
            __syncthreads();
            // stage 2: swapped MFMA, 3 independent 4-deep chains per tile
            short8 Ah[4], Al[4];
#pragma unroll
            for (int ks = 0; ks < 4; ++ks) {
                Ah[ks] = hi8[ks * 64 + lane];
                Al[ks] = lo8[ks * 64 + lane];
            }
            f32x4 hh0 = {b2a[0], b2a[1], b2a[2], b2a[3]};   // b2 in init
            f32x4 hh1 = {b2b[0], b2b[1], b2b[2], b2b[3]};
            f32x4 lh0 = {0.f, 0.f, 0.f, 0.f}, lh1 = {0.f, 0.f, 0.f, 0.f};
            f32x4 hl0 = {0.f, 0.f, 0.f, 0.f}, hl1 = {0.f, 0.f, 0.f, 0.f};
            __builtin_amdgcn_s_setprio(1);               // R25: T5
#pragma unroll
            for (int ks = 0; ks < 4; ++ks) {
                hh0 = __builtin_amdgcn_mfma_f32_16x16x32_bf16(Bh0[ks], Ah[ks], hh0, 0, 0, 0);
                hh1 = __builtin_amdgcn_mfma_f32_16x16x32_bf16(Bh1[ks], Ah[ks], hh1, 0, 0, 0);
                lh0 = __builtin_amdgcn_mfma_f32_16x16x32_bf16(Bh0[ks], Al[ks], lh0, 0, 0, 0);
                lh1 = __builtin_amdgcn_mfma_f32_16x16x32_bf16(Bh1[ks], Al[ks], lh1, 0, 0, 0);
                hl0 = __builtin_amdgcn_mfma_f32_16x16x32_bf16(Bl0[ks], Ah[ks], hl0, 0, 0, 0);
                hl1 = __builtin_amdgcn_mfma_f32_16x16x32_bf16(Bl1[ks], Ah[ks], hl1, 0, 0, 0);
            }
            __builtin_amdgcn_s_setprio(0);
            float fp = 0.0f;
#pragma unroll
            for (int reg = 0; reg < 4; ++reg) {
                float a0v = (hh0[reg] + lh0[reg]) + hl0[reg];
                float a1v = (hh1[reg] + lh1[reg]) + hl1[reg];
                fp = fmaf(fmaxf(a0v, 0.f), w3a[reg], fp);
                fp = fmaf(fmaxf(a1v, 0.f), w3b[reg], fp);
            }
            fp += __shfl_xor(fp, 16, 64);
            fp += __shfl_xor(fp, 32, 64);
            if (lane < 16) fpart[w][lane] = fp;
            __syncthreads();
            float fn = fpart[0][ln15] + fpart[1][ln15] + fpart[2][ln15]
                     + fpart[3][ln15] + b3v;
            bool bel = (fn < 0.0f);
            dlo = bel ? dn  : dlo;  flo = bel ? fn  : flo;
            dhi = bel ? dhi : dn;   fhi = bel ? fhi : fn;
        }
        if (tid < 16 && valid) {
            out[r] = dp;
            out[NR + 3 * r + 0] = fmaf(dp, dx, ox);
            out[NR + 3 * r + 1] = fmaf(dp, dy, oy);
            out[NR + 3 * r + 2] = fmaf(dp, dz, oz);
            out[4 * NR + r] = 1.0f;
        }
    }
}

// ---------------------------------------------------------------------------
extern "C" void kernel_launch(void* const* d_in, const int* in_sizes, int n_in,
                              void* d_out, int out_size, void* d_ws, size_t ws_size,
                              hipStream_t stream)
{
    const float* ray0 = (const float*)d_in[0];
    const float* dirs = (const float*)d_in[1];
    const float* feat = (const float*)d_in[2];
    const float* W1   = (const float*)d_in[3];
    const float* b1   = (const float*)d_in[4];
    const float* W2   = (const float*)d_in[5];
    const float* b2   = (const float*)d_in[6];
    const float* W3   = (const float*)d_in[7];
    const float* b3   = (const float*)d_in[8];
    float* out = (float*)d_out;

    // workspace layout (float offsets), total ~6.1 MB
    float* w      = (float*)d_ws;
    short* w2f    = (short*)w;                        // 32768 bf16 = 16384 f
    float* cva    = w + 16384;                        // 512
    float* f_all  = w + 16896;                        // 1,048,576
    float* stf    = w + 1065472;                      // 262,144 (16B aligned)
    int*   ids    = (int*)(w + 1327616);              // 65,536
    int*   fixlist= (int*)(w + 1393152);              // 131,072
    int*   count  = (int*)(w + 1524224);
    int*   fixcnt = (int*)(w + 1524225);

    k_setup <<<16,   256, 0, stream>>>(W1, b1, W2, feat, cva, w2f, count, fixcnt);
    k_marchx<<<1024, 256, 0, stream>>>(ray0, dirs, W1, cva, b2, W3, b3, w2f,
                                       f_all, fixlist, fixcnt);
    k_fix   <<<1024, 256, 0, stream>>>(ray0, dirs, W1, cva, W2, b2, W3, b3,
                                       fixcnt, fixlist, f_all);
    k_cross <<<NR / 256, 256, 0, stream>>>(ray0, dirs, f_all, count, ids,
                                           (float4*)stf, out);
    // R25: 1 group/block, idle blocks exit pre-prologue.
    k_refine<<<4096, 256, 0, stream>>>(ray0, dirs, W1, cva, b2, W3, b3, w2f,
                                       count, ids, (const float4*)stf, out);
}

// Round 7
// 181.335 us; speedup vs baseline: 1.0425x; 1.0425x over previous
//
#include <hip/hip_runtime.h>
#include <hip/hip_bf16.h>

typedef short short8 __attribute__((ext_vector_type(8)));
typedef float f32x4  __attribute__((ext_vector_type(4)));

static constexpr int   NPB  = 16384;
static constexpr int   NR   = 4 * NPB;       // 65536 rays
static constexpr int   NS   = 16;
static constexpr int   H    = 128;
static constexpr int   NPTS = NR * NS;       // 1,048,576 march points
static constexpr int   NCHUNK2 = NR / 8;     // 8192 chunks of 8 rays x 16 steps
static constexpr int   FIXCAP = 131072;
static constexpr float FARV = 2.4f;
static constexpr float EPSF = 1.1920928955078125e-07f;
// march f error with A=bf16-RNE only (W2 hi+lo): RMS ~1e-3, worst ~0.03.
// R9/R13 proved this config correctness-safe at FTHRESH=0.03.
static constexpr float FTHRESH = 0.03f;

// NOTE (R12): never declare __launch_bounds__ > 2 waves/EU on MFMA kernels.
// NOTE (R15): do NOT interleave stage1(c+1) VALU with stage2(c) MFMA.
// NOTE (R17/R18): extra barrier removal, mt-unroll, accumulator-split all
// neutral — compiler schedule already optimal; residual idle is barrier-drain.
// NOTE (R21/R21b): affine stage-1; arch-VGPR drop raised occupancy 19->33%.
// NOTE (R22/R24): k_fix wave-per-point + 4-pt batching; now ~5us.
// NOTE (R23): swapped MFMA (C[n][point]); march structure-bound
// (MFMA 33% + VALU 41% + ~25% barrier-drain idle at 2.75 blk/CU).
// NOTE (R25): refine bracket-seeding from k_cross (state.y/.w), 1 group per
// block, pre-prologue idle exit: net ~-3us. Refine is ~15-20us post-R24,
// NOT ~40us — decomposition estimate corrected.
// NOTE (R26): s_setprio around MFMA REGRESSED march 83->91.5us: hipcc treats
// it as a sched fence -> VGPR 64->72 -> occupancy 33->22%. NEVER use setprio
// in these kernels. Reverted.

// ---------------- bf16 helpers ---------------------------------------------
__device__ __forceinline__ unsigned bf16hi(float x) {
    unsigned u = __float_as_uint(x);
    return (u + 0x7FFFu + ((u >> 16) & 1u)) >> 16;
}
__device__ __forceinline__ void split_bf16(float x, short& hi, short& lo) {
    unsigned h = bf16hi(x);
    float hf = __uint_as_float(h << 16);
    unsigned l = __float_as_uint(x - hf) >> 16;
    hi = (short)h; lo = (short)l;
}
// packed RNE f32x2 -> bf16x2 (v_cvt_pk_bf16_f32 on gfx950)
__device__ __forceinline__ unsigned pk_bf16(float a, float b) {
    __hip_bfloat162 p = __float22bfloat162_rn(make_float2(a, b));
    unsigned u;
    __builtin_memcpy(&u, &p, sizeof(u));
    return u;
}

// ---------------- setup: cv vectors + W2 MFMA packing + counters -----------
__global__ void k_setup(const float* __restrict__ W1, const float* __restrict__ b1,
                        const float* __restrict__ W2, const float* __restrict__ feat,
                        float* __restrict__ cva, short* __restrict__ w2f,
                        int* __restrict__ count, int* __restrict__ fixcnt)
{
    int t = blockIdx.x * blockDim.x + threadIdx.x;   // 4096 threads
    if (t == 0) { *count = 0; *fixcnt = 0; }
    if (t < 4 * H) {                                 // cv = b1 + feat @ W1[3:35]
        int b = t >> 7, kk = t & (H - 1);
        float acc = b1[kk];
#pragma unroll
        for (int i = 0; i < 32; ++i)
            acc = fmaf(feat[b * 32 + i], W1[(3 + i) * H + kk], acc);
        cva[b * H + kk] = acc;
    }
    {                                                // MFMA W2-fragments (hi/lo)
        int lane = t & 63, ks = (t >> 6) & 3, part = (t >> 8) & 1;
        int nt = (t >> 9) & 1, w = (t >> 10) & 3;
        int n = w * 32 + nt * 16 + (lane & 15);
        int kb = ks * 32 + (lane >> 4) * 8;
        short8 v;
#pragma unroll
        for (int j = 0; j < 8; ++j) {
            short hi, lo;
            split_bf16(W2[(kb + j) * H + n], hi, lo);
            v[j] = part ? lo : hi;
        }
        ((short8*)w2f)[((w * 4 + nt * 2 + part) * 4 + ks) * 64 + lane] = v;
    }
}

// ---------------- Phase A: MFMA march (8 rays x 16 steps per chunk) --------
// R13 numerics; R21b affine stage 1; R23 swapped-operand stage 2.
// Point order in chunk: m = s*8 + rr; tile mt = s>>1, B-col = (s&1)*8+rr.
__global__ __launch_bounds__(256, 2) void k_marchx(
    const float* __restrict__ ray0, const float* __restrict__ dirs,
    const float* __restrict__ W1,   const float* __restrict__ cva,
    const float* __restrict__ b2,   const float* __restrict__ W3,
    const float* __restrict__ b3p,  const short* __restrict__ w2f,
    float* __restrict__ f_all, int* __restrict__ fixlist, int* __restrict__ fixcnt)
{
    __shared__ __align__(16) short hAhi[16384];      // 128 pts x 128 k (32 KB)
    __shared__ float fpart[2][4][128];               // ping-pong
    const int tid = threadIdx.x;
    const int w = tid >> 6, lane = tid & 63;
    const int q = lane >> 4, ln15 = lane & 15;

    const short8* wf8 = (const short8*)w2f;
    short8 Bh0[4], Bl0[4], Bh1[4], Bl1[4];
#pragma unroll
    for (int ks = 0; ks < 4; ++ks) {
        Bh0[ks] = wf8[((w * 4 + 0) * 4 + ks) * 64 + lane];
        Bl0[ks] = wf8[((w * 4 + 1) * 4 + ks) * 64 + lane];
        Bh1[ks] = wf8[((w * 4 + 2) * 4 + ks) * 64 + lane];
        Bl1[ks] = wf8[((w * 4 + 3) * 4 + ks) * 64 + lane];
    }
    // R23: per-lane n-axis constants (n = w*32 + [0,16) + q*4 + reg)
    const int nb0 = w * 32 + q * 4;
    float b2a[4], b2b[4], w3a[4], w3b[4];
#pragma unroll
    for (int reg = 0; reg < 4; ++reg) {
        b2a[reg] = b2[nb0 + reg];       b2b[reg] = b2[nb0 + 16 + reg];
        w3a[reg] = W3[nb0 + reg];       w3b[reg] = W3[nb0 + 16 + reg];
    }
    const float b3v  = *b3p;

    // ---- stage-1 thread-constant setup (affine stage 1) ----
    const int rr = tid & 7;                 // ray within chunk
    const int kt = tid >> 3;                // k-quad index, k = 4*kt..4*kt+3
    const int qp = (tid >> 4) & 3;
    const int j0 = ((tid >> 3) & 1) * 4;
    short* hwp = hAhi + ((w * 64 + rr + 16 * qp) * 8 + j0);
    const float4 wxv = ((const float4*)W1)[kt];
    const float4 wyv = ((const float4*)(W1 + H))[kt];
    const float4 wzv = ((const float4*)(W1 + 2 * H))[kt];

    int pp = 0;
    for (int c = blockIdx.x; c < NCHUNK2; c += gridDim.x) {
        // ---- stage 1: base/slope per (ray, 4k), then 16 steps x 1 fma/k
        {
            int r = c * 8 + rr;
            float ox = ray0[3 * r], oy = ray0[3 * r + 1], oz = ray0[3 * r + 2];
            float dx = dirs[3 * r], dy = dirs[3 * r + 1], dz = dirs[3 * r + 2];
            const float4 cvv = ((const float4*)(cva + (r >> 14) * H))[kt];
            float bb0 = fmaf(ox, wxv.x, fmaf(oy, wyv.x, fmaf(oz, wzv.x, cvv.x)));
            float bb1 = fmaf(ox, wxv.y, fmaf(oy, wyv.y, fmaf(oz, wzv.y, cvv.y)));
            float bb2 = fmaf(ox, wxv.z, fmaf(oy, wyv.z, fmaf(oz, wzv.z, cvv.z)));
            float bb3 = fmaf(ox, wxv.w, fmaf(oy, wyv.w, fmaf(oz, wzv.w, cvv.w)));
            float sl0 = fmaf(dx, wxv.x, fmaf(dy, wyv.x, dz * wzv.x));
            float sl1 = fmaf(dx, wxv.y, fmaf(dy, wyv.y, dz * wzv.y));
            float sl2 = fmaf(dx, wxv.z, fmaf(dy, wyv.z, dz * wzv.z));
            float sl3 = fmaf(dx, wxv.w, fmaf(dy, wyv.w, dz * wzv.w));
#pragma unroll
            for (int s = 0; s < NS; ++s) {
                const float d = ((float)s * (1.0f / 15.0f)) * FARV;
                float h0 = fmaxf(fmaf(d, sl0, bb0), 0.0f);
                float h1 = fmaxf(fmaf(d, sl1, bb1), 0.0f);
                float h2 = fmaxf(fmaf(d, sl2, bb2), 0.0f);
                float h3 = fmaxf(fmaf(d, sl3, bb3), 0.0f);
                uint2 u;
                u.x = pk_bf16(h0, h1);
                u.y = pk_bf16(h2, h3);
                // per-s offset (shorts): (s>>1)*2048 + (s&1)*64  (compile-time)
                *(uint2*)(hwp + ((s >> 1) * 2048 + (s & 1) * 64)) = u;
            }
        }
        __syncthreads();
        // ---- stage 2: swapped MFMA per 16-point M-tile: C[n][point]
        const short8* hi8 = (const short8*)hAhi;
#pragma unroll 2
        for (int mt = 0; mt < 8; ++mt) {
            short8 Hh[4];
#pragma unroll
            for (int ks = 0; ks < 4; ++ks)
                Hh[ks] = hi8[(mt * 4 + ks) * 64 + lane];
            f32x4 a0 = {b2a[0], b2a[1], b2a[2], b2a[3]};  // b2 in acc init
            f32x4 a1 = {b2b[0], b2b[1], b2b[2], b2b[3]};
#pragma unroll
            for (int ks = 0; ks < 4; ++ks) {
                a0 = __builtin_amdgcn_mfma_f32_16x16x32_bf16(Bh0[ks], Hh[ks], a0, 0, 0, 0);
                a1 = __builtin_amdgcn_mfma_f32_16x16x32_bf16(Bh1[ks], Hh[ks], a1, 0, 0, 0);
                a0 = __builtin_amdgcn_mfma_f32_16x16x32_bf16(Bl0[ks], Hh[ks], a0, 0, 0, 0);
                a1 = __builtin_amdgcn_mfma_f32_16x16x32_bf16(Bl1[ks], Hh[ks], a1, 0, 0, 0);
            }
            float fp0 = 0.0f, fp1 = 0.0f;
#pragma unroll
            for (int reg = 0; reg < 4; ++reg) {
                fp0 = fmaf(fmaxf(a0[reg], 0.f), w3a[reg], fp0);
                fp1 = fmaf(fmaxf(a1[reg], 0.f), w3b[reg], fp1);
            }
            float fp = fp0 + fp1;
            fp += __shfl_xor(fp, 16, 64);   // reduce over q (n-groups)
            fp += __shfl_xor(fp, 32, 64);
            if (lane < 16) fpart[pp][w][mt * 16 + lane] = fp;
        }
        __syncthreads();
        // ---- stage 3: finalize 128 points (fpart ping-pong: no 3rd barrier)
        if (tid < 128) {
            float f = fpart[pp][0][tid] + fpart[pp][1][tid] + fpart[pp][2][tid]
                    + fpart[pp][3][tid] + b3v;
            int s = tid >> 3, rb = tid & 7;
            int P = s * NR + c * 8 + rb;             // same s*NR+r encoding
            f_all[P] = f;
            if (fabsf(f) < FTHRESH) {
                int sl = atomicAdd(fixcnt, 1);
                if (sl < FIXCAP) fixlist[sl] = P;
            }
        }
        pp ^= 1;
    }
}

// ---------------- fp32 re-eval of near-zero points (4 pts/wave, R24) -------
__global__ __launch_bounds__(256) void k_fix(
    const float* __restrict__ ray0, const float* __restrict__ dirs,
    const float* __restrict__ W1,   const float* __restrict__ cva,
    const float* __restrict__ W2,   const float* __restrict__ b2,
    const float* __restrict__ W3,   const float* __restrict__ b3p,
    const int* __restrict__ fixcnt, const int* __restrict__ fixlist,
    float* __restrict__ f_all)
{
    __shared__ __align__(16) float hsh[4][128][4];   // [wave][k][point], 8 KB
    const int wv = threadIdx.x >> 6, lane = threadIdx.x & 63;
    unsigned fc = (unsigned)*fixcnt;
    if (fc > (unsigned)FIXCAP) fc = FIXCAP;

    const float w1x0 = W1[lane],           w1x1 = W1[64 + lane];
    const float w1y0 = W1[H + lane],       w1y1 = W1[H + 64 + lane];
    const float w1z0 = W1[2 * H + lane],   w1z1 = W1[2 * H + 64 + lane];
    const float w30  = W3[lane],           w31  = W3[64 + lane];
    const float b20  = b2[lane],           b21  = b2[64 + lane];
    const float b3v  = *b3p;

    for (unsigned i0 = (blockIdx.x * 4u + (unsigned)wv) * 4u; i0 < fc;
         i0 += gridDim.x * 16u) {
        int Pj[4];
#pragma unroll
        for (int j = 0; j < 4; ++j) {
            unsigned i = i0 + (unsigned)j;
            bool vld = (i < fc);
            int P = fixlist[vld ? i : i0] & (NPTS - 1);
            Pj[j] = vld ? P : -1;
            int r = P & (NR - 1), s = P >> 16;
            float d = ((float)s * (1.0f / 15.0f)) * FARV;
            float ox = ray0[3 * r], oy = ray0[3 * r + 1], oz = ray0[3 * r + 2];
            float dx = dirs[3 * r], dy = dirs[3 * r + 1], dz = dirs[3 * r + 2];
            float px = fmaf(d, dx, ox), py = fmaf(d, dy, oy), pz = fmaf(d, dz, oz);
            const float* __restrict__ cv = cva + (r >> 14) * H;
            float h0 = fmaf(px, w1x0, fmaf(py, w1y0, fmaf(pz, w1z0, cv[lane])));
            float h1 = fmaf(px, w1x1, fmaf(py, w1y1, fmaf(pz, w1z1, cv[64 + lane])));
            hsh[wv][lane][j]      = fmaxf(h0, 0.0f);
            hsh[wv][lane + 64][j] = fmaxf(h1, 0.0f);
        }
        // same-wave LDS write->read; compiler inserts the lgkmcnt wait.
        float a0[4] = {b20, b20, b20, b20};
        float a1[4] = {b21, b21, b21, b21};
#pragma unroll 4
        for (int k = 0; k < H; ++k) {
            float4 hk = *(const float4*)&hsh[wv][k][0];  // broadcast b128
            float w2l = W2[k * H + lane];
            float w2h = W2[k * H + 64 + lane];
            a0[0] = fmaf(hk.x, w2l, a0[0]);  a1[0] = fmaf(hk.x, w2h, a1[0]);
            a0[1] = fmaf(hk.y, w2l, a0[1]);  a1[1] = fmaf(hk.y, w2h, a1[1]);
            a0[2] = fmaf(hk.z, w2l, a0[2]);  a1[2] = fmaf(hk.z, w2h, a1[2]);
            a0[3] = fmaf(hk.w, w2l, a0[3]);  a1[3] = fmaf(hk.w, w2h, a1[3]);
        }
#pragma unroll
        for (int j = 0; j < 4; ++j) {
            float f = fmaf(fmaxf(a0[j], 0.f), w30, fmaxf(a1[j], 0.f) * w31);
#pragma unroll
            for (int off = 32; off; off >>= 1)
                f += __shfl_xor(f, off, 64);
            if (lane == 0 && Pj[j] >= 0) f_all[Pj[j]] = f + b3v;
        }
    }
}

// ---------------- crossing scan --------------------------------------------
// R25: state carries (dlo, f_low, dhi, f_high) — refine seeds from these.
__global__ void k_cross(
    const float* __restrict__ ray0, const float* __restrict__ dirs,
    const float* __restrict__ f_all,
    int* __restrict__ count, int* __restrict__ ids,
    float4* __restrict__ state, float* __restrict__ out)
{
    int r = blockIdx.x * blockDim.x + threadIdx.x;   // 65536 threads
    float fv[NS];
#pragma unroll
    for (int s = 0; s < NS; ++s) fv[s] = f_all[s * NR + r];
    int idx = -1;
#pragma unroll
    for (int s = NS - 2; s >= 0; --s) {
        if (fv[s] < 0.0f && fv[s + 1] >= 0.0f) idx = s;
    }
    if (idx < 0) {
        float ox = ray0[3 * r], oy = ray0[3 * r + 1], oz = ray0[3 * r + 2];
        float dx = dirs[3 * r], dy = dirs[3 * r + 1], dz = dirs[3 * r + 2];
        out[r] = FARV;
        out[NR + 3 * r + 0] = fmaf(FARV, dx, ox);
        out[NR + 3 * r + 1] = fmaf(FARV, dy, oy);
        out[NR + 3 * r + 2] = fmaf(FARV, dz, oz);
        out[4 * NR + r] = 0.0f;
    } else {
        int slot = atomicAdd(count, 1);
        ids[slot] = r;
        float flo = fv[idx], fhi = fv[idx + 1];
        float dlo = ((float)idx * (1.0f / 15.0f)) * FARV;
        float dhi = ((float)(idx + 1) * (1.0f / 15.0f)) * FARV;
        state[slot] = make_float4(dlo, flo, dhi, fhi);
    }
}

// ---------------- Phase B: MFMA secant refine (16 rays per block) ----------
// R13 structure; R23 swapped operands. R25: brackets seeded from state
// (reference semantics — no it0/1 re-eval): 8 secant rounds + final formula.
// Grid 4096 >= max groups: exactly 1 group per block; idle blocks return
// before the fragment prologue. R26: no setprio.
__global__ __launch_bounds__(256, 2) void k_refine(
    const float* __restrict__ ray0, const float* __restrict__ dirs,
    const float* __restrict__ W1,   const float* __restrict__ cva,
    const float* __restrict__ b2,   const float* __restrict__ W3,
    const float* __restrict__ b3p,  const short* __restrict__ w2f,
    const int* __restrict__ count,  const int* __restrict__ ids,
    const float4* __restrict__ state, float* __restrict__ out)
{
    __shared__ __align__(16) short hAhi[2048];       // 4 ks x 64 lanes x short8
    __shared__ __align__(16) short hAlo[2048];
    __shared__ float fpart[4][16];
    const int tid = threadIdx.x;
    const int w = tid >> 6, lane = tid & 63;
    const int q = lane >> 4, ln15 = lane & 15;

    unsigned cnt = (unsigned)*count;
    if (cnt > (unsigned)NR) cnt = (unsigned)NR;      // poison guard
    const unsigned g = blockIdx.x;                   // 1 group per block
    if (g * 16u >= cnt) return;                      // R25: pre-prologue exit

    const short8* wf8 = (const short8*)w2f;
    short8 Bh0[4], Bl0[4], Bh1[4], Bl1[4];
#pragma unroll
    for (int ks = 0; ks < 4; ++ks) {
        Bh0[ks] = wf8[((w * 4 + 0) * 4 + ks) * 64 + lane];
        Bl0[ks] = wf8[((w * 4 + 1) * 4 + ks) * 64 + lane];
        Bh1[ks] = wf8[((w * 4 + 2) * 4 + ks) * 64 + lane];
        Bl1[ks] = wf8[((w * 4 + 3) * 4 + ks) * 64 + lane];
    }
    // R23 per-lane n-axis constants
    const int nb0 = w * 32 + q * 4;
    float b2a[4], b2b[4], w3a[4], w3b[4];
#pragma unroll
    for (int reg = 0; reg < 4; ++reg) {
        b2a[reg] = b2[nb0 + reg];       b2b[reg] = b2[nb0 + 16 + reg];
        w3a[reg] = W3[nb0 + reg];       w3b[reg] = W3[nb0 + 16 + reg];
    }
    const float b3v  = *b3p;

    const int i4 = (w * 32 + q * 8) >> 2;
    const float4* W1x4 = (const float4*)(W1);
    const float4* W1y4 = (const float4*)(W1 + H);
    const float4* W1z4 = (const float4*)(W1 + 2 * H);
    const float4 x0 = W1x4[i4], x1 = W1x4[i4 + 1];
    const float4 y0 = W1y4[i4], y1 = W1y4[i4 + 1];
    const float4 z0 = W1z4[i4], z1 = W1z4[i4 + 1];

    uint4* hi4 = (uint4*)hAhi;
    uint4* lo4 = (uint4*)hAlo;
    const short8* hi8 = (const short8*)hAhi;
    const short8* lo8 = (const short8*)hAlo;

    {
        unsigned t = g * 16u + (unsigned)ln15;
        bool valid = (t < cnt);
        unsigned tc = valid ? t : (cnt - 1);
        int r = ids[tc] & (NR - 1);                  // poison guard
        float4 st = state[tc];
        float dlo = st.x, dhi = st.z;
        float flo = st.y, fhi = st.w;                // R25: seeded brackets
        float ox = ray0[3 * r], oy = ray0[3 * r + 1], oz = ray0[3 * r + 2];
        float dx = dirs[3 * r], dy = dirs[3 * r + 1], dz = dirs[3 * r + 2];
        const float4* cv4 = (const float4*)(cva + (r >> 14) * H);
        float4 c0 = cv4[i4], c1 = cv4[i4 + 1];
        float dp = 0.0f;

#pragma unroll 1
        for (int it = 0; it < 9; ++it) {
            // it 0..7: secant eval rounds; it 8: final formula only
            float dc  = fhi - flo;
            float den = copysignf(fmaxf(fabsf(dc), EPSF), dc);
            float dn  = dlo - (flo * (dhi - dlo)) / den;
            if (it == 8) { dp = dn; break; }
            // stage 1: h for ray ln15, 8 k values -> hi/lo bf16 -> LDS
            float px = fmaf(dn, dx, ox), py = fmaf(dn, dy, oy), pz = fmaf(dn, dz, oz);
            float hv[8];
            hv[0] = fmaf(px, x0.x, fmaf(py, y0.x, fmaf(pz, z0.x, c0.x)));
            hv[1] = fmaf(px, x0.y, fmaf(py, y0.y, fmaf(pz, z0.y, c0.y)));
            hv[2] = fmaf(px, x0.z, fmaf(py, y0.z, fmaf(pz, z0.z, c0.z)));
            hv[3] = fmaf(px, x0.w, fmaf(py, y0.w, fmaf(pz, z0.w, c0.w)));
            hv[4] = fmaf(px, x1.x, fmaf(py, y1.x, fmaf(pz, z1.x, c1.x)));
            hv[5] = fmaf(px, x1.y, fmaf(py, y1.y, fmaf(pz, z1.y, c1.y)));
            hv[6] = fmaf(px, x1.z, fmaf(py, y1.z, fmaf(pz, z1.z, c1.z)));
            hv[7] = fmaf(px, x1.w, fmaf(py, y1.w, fmaf(pz, z1.w, c1.w)));
            unsigned uh[4], ul[4];
#pragma unroll
            for (int jp = 0; jp < 4; ++jp) {
                float h0 = fmaxf(hv[2 * jp],     0.0f);
                float h1 = fmaxf(hv[2 * jp + 1], 0.0f);
                unsigned u = pk_bf16(h0, h1);
                float hf0 = __uint_as_float(u << 16);
                float hf1 = __uint_as_float(u & 0xFFFF0000u);
                ul[jp] = pk_bf16(h0 - hf0, h1 - hf1);
                uh[jp] = u;
            }
            hi4[w * 64 + lane] = make_uint4(uh[0], uh[1], uh[2], uh[3]);
            lo4[w * 64 + lane] = make_uint4(ul[0], ul[1], ul[2], ul[3]);
            __syncthreads();
            // stage 2: swapped MFMA, 3 independent 4-deep chains per tile
            short8 Ah[4], Al[4];
#pragma unroll
            for (int ks = 0; ks < 4; ++ks) {
                Ah[ks] = hi8[ks * 64 + lane];
                Al[ks] = lo8[ks * 64 + lane];
            }
            f32x4 hh0 = {b2a[0], b2a[1], b2a[2], b2a[3]};   // b2 in init
            f32x4 hh1 = {b2b[0], b2b[1], b2b[2], b2b[3]};
            f32x4 lh0 = {0.f, 0.f, 0.f, 0.f}, lh1 = {0.f, 0.f, 0.f, 0.f};
            f32x4 hl0 = {0.f, 0.f, 0.f, 0.f}, hl1 = {0.f, 0.f, 0.f, 0.f};
#pragma unroll
            for (int ks = 0; ks < 4; ++ks) {
                hh0 = __builtin_amdgcn_mfma_f32_16x16x32_bf16(Bh0[ks], Ah[ks], hh0, 0, 0, 0);
                hh1 = __builtin_amdgcn_mfma_f32_16x16x32_bf16(Bh1[ks], Ah[ks], hh1, 0, 0, 0);
                lh0 = __builtin_amdgcn_mfma_f32_16x16x32_bf16(Bh0[ks], Al[ks], lh0, 0, 0, 0);
                lh1 = __builtin_amdgcn_mfma_f32_16x16x32_bf16(Bh1[ks], Al[ks], lh1, 0, 0, 0);
                hl0 = __builtin_amdgcn_mfma_f32_16x16x32_bf16(Bl0[ks], Ah[ks], hl0, 0, 0, 0);
                hl1 = __builtin_amdgcn_mfma_f32_16x16x32_bf16(Bl1[ks], Ah[ks], hl1, 0, 0, 0);
            }
            float fp = 0.0f;
#pragma unroll
            for (int reg = 0; reg < 4; ++reg) {
                float a0v = (hh0[reg] + lh0[reg]) + hl0[reg];
                float a1v = (hh1[reg] + lh1[reg]) + hl1[reg];
                fp = fmaf(fmaxf(a0v, 0.f), w3a[reg], fp);
                fp = fmaf(fmaxf(a1v, 0.f), w3b[reg], fp);
            }
            fp += __shfl_xor(fp, 16, 64);
            fp += __shfl_xor(fp, 32, 64);
            if (lane < 16) fpart[w][lane] = fp;
            __syncthreads();
            float fn = fpart[0][ln15] + fpart[1][ln15] + fpart[2][ln15]
                     + fpart[3][ln15] + b3v;
            bool bel = (fn < 0.0f);
            dlo = bel ? dn  : dlo;  flo = bel ? fn  : flo;
            dhi = bel ? dhi : dn;   fhi = bel ? fhi : fn;
        }
        if (tid < 16 && valid) {
            out[r] = dp;
            out[NR + 3 * r + 0] = fmaf(dp, dx, ox);
            out[NR + 3 * r + 1] = fmaf(dp, dy, oy);
            out[NR + 3 * r + 2] = fmaf(dp, dz, oz);
            out[4 * NR + r] = 1.0f;
        }
    }
}

// ---------------------------------------------------------------------------
extern "C" void kernel_launch(void* const* d_in, const int* in_sizes, int n_in,
                              void* d_out, int out_size, void* d_ws, size_t ws_size,
                              hipStream_t stream)
{
    const float* ray0 = (const float*)d_in[0];
    const float* dirs = (const float*)d_in[1];
    const float* feat = (const float*)d_in[2];
    const float* W1   = (const float*)d_in[3];
    const float* b1   = (const float*)d_in[4];
    const float* W2   = (const float*)d_in[5];
    const float* b2   = (const float*)d_in[6];
    const float* W3   = (const float*)d_in[7];
    const float* b3   = (const float*)d_in[8];
    float* out = (float*)d_out;

    // workspace layout (float offsets), total ~6.1 MB
    float* w      = (float*)d_ws;
    short* w2f    = (short*)w;                        // 32768 bf16 = 16384 f
    float* cva    = w + 16384;                        // 512
    float* f_all  = w + 16896;                        // 1,048,576
    float* stf    = w + 1065472;                      // 262,144 (16B aligned)
    int*   ids    = (int*)(w + 1327616);              // 65,536
    int*   fixlist= (int*)(w + 1393152);              // 131,072
    int*   count  = (int*)(w + 1524224);
    int*   fixcnt = (int*)(w + 1524225);

    k_setup <<<16,   256, 0, stream>>>(W1, b1, W2, feat, cva, w2f, count, fixcnt);
    k_marchx<<<1024, 256, 0, stream>>>(ray0, dirs, W1, cva, b2, W3, b3, w2f,
                                       f_all, fixlist, fixcnt);
    k_fix   <<<1024, 256, 0, stream>>>(ray0, dirs, W1, cva, W2, b2, W3, b3,
                                       fixcnt, fixlist, f_all);
    k_cross <<<NR / 256, 256, 0, stream>>>(ray0, dirs, f_all, count, ids,
                                           (float4*)stf, out);
    // R25: 1 group/block, idle blocks exit pre-prologue.
    k_refine<<<4096, 256, 0, stream>>>(ray0, dirs, W1, cva, b2, W3, b3, w2f,
                                       count, ids, (const float4*)stf, out);
}